// Round 1
// baseline (608.607 us; speedup 1.0000x reference)
//
#include <hip/hip_runtime.h>
#include <cstdint>
#include <cstddef>

// ---------------- CSR build ----------------
__global__ void count_edges_k(const int* __restrict__ dst, int E, int* __restrict__ cnt) {
  int e = blockIdx.x * blockDim.x + threadIdx.x;
  if (e < E) atomicAdd(&cnt[dst[e]], 1);
}

__global__ void scan1_k(const int* __restrict__ cnt, int* __restrict__ rs,
                        int* __restrict__ partials, int n) {
  __shared__ int s[1024];
  int t = threadIdx.x;
  int gid = blockIdx.x * 1024 + t;
  int v = (gid < n) ? cnt[gid] : 0;
  s[t] = v;
  __syncthreads();
  for (int off = 1; off < 1024; off <<= 1) {
    int u = (t >= off) ? s[t - off] : 0;
    __syncthreads();
    s[t] += u;
    __syncthreads();
  }
  if (gid < n) rs[gid] = s[t] - v;            // block-local exclusive scan
  if (t == 1023) partials[blockIdx.x] = s[1023];
}

__global__ void scan2_k(int* __restrict__ partials, int nb) {
  if (threadIdx.x == 0 && blockIdx.x == 0) {
    int acc = 0;
    for (int i = 0; i < nb; i++) { int v = partials[i]; partials[i] = acc; acc += v; }
  }
}

__global__ void scan3_k(int* __restrict__ rs, int* __restrict__ cursor,
                        const int* __restrict__ partials, int n, int total) {
  int gid = blockIdx.x * blockDim.x + threadIdx.x;
  if (gid < n) {
    int v = rs[gid] + partials[gid >> 10];
    rs[gid] = v;
    cursor[gid] = v;
  }
  if (gid == 0) rs[n] = total;
}

__global__ void dinv_k(const int* __restrict__ cnt, float* __restrict__ dinv, int n) {
  int i = blockIdx.x * blockDim.x + threadIdx.x;
  if (i < n) dinv[i] = rsqrtf((float)cnt[i] + 1.0f);   // +1 = self loop; deg>=1 always
}

__global__ void fill_csr_k(const int* __restrict__ src, const int* __restrict__ dst, int E,
                           int* __restrict__ cursor, const float* __restrict__ dinv,
                           int* __restrict__ col, float* __restrict__ nrm) {
  int e = blockIdx.x * blockDim.x + threadIdx.x;
  if (e < E) {
    int d = dst[e], s = src[e];
    int pos = atomicAdd(&cursor[d], 1);
    col[pos] = s;
    nrm[pos] = dinv[s] * dinv[d];
  }
}

// ---------------- dense GEMM: C[N,128] = A[N,128] @ W[128,128] ----------------
// block tile: 32 rows x 64 cols (grid.y=2 col halves). Ws 32KB + As ~17KB < 64KB -> 3 blocks/CU.
__global__ __launch_bounds__(256) void gemm_k(const float* __restrict__ A,
                                              const float* __restrict__ W,
                                              float* __restrict__ C, int N) {
  __shared__ float Ws[128 * 64];
  __shared__ float As[32][132];   // +4 pad: As[r][k] reads spread banks
  const int c0 = blockIdx.y * 64;
  const int r0 = blockIdx.x * 32;
  {
    const float4* W4 = (const float4*)W;
    float4* Ws4 = (float4*)Ws;
    for (int idx = threadIdx.x; idx < 2048; idx += 256) {
      int k = idx >> 4;
      int c4 = idx & 15;
      Ws4[idx] = W4[k * 32 + (c0 >> 2) + c4];
    }
  }
  for (int idx = threadIdx.x; idx < 1024; idx += 256) {
    int rr = idx >> 5;
    int c4 = idx & 31;
    int r = r0 + rr;
    float4 v = make_float4(0.f, 0.f, 0.f, 0.f);
    if (r < N) v = ((const float4*)(A + (size_t)r * 128))[c4];
    *(float4*)&As[rr][c4 * 4] = v;
  }
  __syncthreads();
  const int tx = threadIdx.x & 15;   // 16 x 4 cols
  const int ty = threadIdx.x >> 4;   // 16 x 2 rows
  float acc[2][4] = {};
  #pragma unroll 8
  for (int k = 0; k < 128; k++) {
    float4 wv = *(const float4*)&Ws[k * 64 + tx * 4];
    float a0 = As[ty * 2 + 0][k];
    float a1 = As[ty * 2 + 1][k];
    acc[0][0] += a0 * wv.x; acc[0][1] += a0 * wv.y; acc[0][2] += a0 * wv.z; acc[0][3] += a0 * wv.w;
    acc[1][0] += a1 * wv.x; acc[1][1] += a1 * wv.y; acc[1][2] += a1 * wv.z; acc[1][3] += a1 * wv.w;
  }
  #pragma unroll
  for (int i = 0; i < 2; i++) {
    int r = r0 + ty * 2 + i;
    if (r < N) {
      float4 o = make_float4(acc[i][0], acc[i][1], acc[i][2], acc[i][3]);
      *(float4*)(C + (size_t)r * 128 + c0 + tx * 4) = o;
    }
  }
}

// ---------------- neighbor aggregation (CSR gather-reduce, one wave per node) ----------------
__global__ __launch_bounds__(256) void agg_k(const float* __restrict__ h,
                                             const int* __restrict__ rs,
                                             const int* __restrict__ col,
                                             const float* __restrict__ nrm,
                                             const float* __restrict__ dinv,
                                             const float* __restrict__ bias,
                                             float* __restrict__ out, int n) {
  int wid = (blockIdx.x * blockDim.x + threadIdx.x) >> 6;
  int lane = threadIdx.x & 63;
  if (wid >= n) return;
  float di = dinv[wid];
  const float* hrow = h + (size_t)wid * 128;
  float acc0 = hrow[lane] * (di * di);          // self loop
  float acc1 = hrow[64 + lane] * (di * di);
  int beg = rs[wid], end = rs[wid + 1];
  for (int base = beg; base < end; base += 64) {
    int m = end - base; if (m > 64) m = 64;
    int sidx = 0; float w = 0.f;
    if (lane < m) { sidx = col[base + lane]; w = nrm[base + lane]; }
    for (int j = 0; j < m; j++) {
      int s = __shfl(sidx, j);
      float nv = __shfl(w, j);
      const float* hs = h + (size_t)s * 128;
      acc0 += hs[lane] * nv;
      acc1 += hs[64 + lane] * nv;
    }
  }
  out[(size_t)wid * 128 + lane] = fmaxf(acc0 + bias[lane], 0.f);
  out[(size_t)wid * 128 + 64 + lane] = fmaxf(acc1 + bias[64 + lane], 0.f);
}

// ---------------- per-graph mean pool (batch sorted; run-accumulate then atomic) ----------------
__global__ void pool_k(const float* __restrict__ h, const int* __restrict__ batch, int n,
                       float* __restrict__ pool, float* __restrict__ gcnt) {
  int f = threadIdx.x;          // 0..127
  int n0 = blockIdx.x * 64;
  if (n0 >= n) return;
  int n1 = n0 + 64; if (n1 > n) n1 = n;
  int gcur = batch[n0];
  float acc = 0.f, cacc = 0.f;
  for (int i = n0; i < n1; i++) {
    int g = batch[i];
    if (g != gcur) {
      atomicAdd(&pool[gcur * 128 + f], acc);
      if (f == 0) atomicAdd(&gcnt[gcur], cacc);
      acc = 0.f; cacc = 0.f; gcur = g;
    }
    acc += h[(size_t)i * 128 + f];
    cacc += 1.f;
  }
  atomicAdd(&pool[gcur * 128 + f], acc);
  if (f == 0) atomicAdd(&gcnt[gcur], cacc);
}

// ---------------- classifier head: one block per graph ----------------
__global__ void classify_k(const float* __restrict__ pool, const float* __restrict__ gcnt,
                           const float* __restrict__ Wc1, const float* __restrict__ bc1,
                           const float* __restrict__ Wc2, const float* __restrict__ bc2,
                           float* __restrict__ out, int nc) {
  __shared__ float gs[128];
  __shared__ float zs[128];
  int g = blockIdx.x, t = threadIdx.x;
  float c = gcnt[g]; if (c < 1.f) c = 1.f;
  gs[t] = pool[g * 128 + t] / c;
  __syncthreads();
  float acc = bc1[t];
  for (int k = 0; k < 128; k++) acc += gs[k] * Wc1[k * 128 + t];
  zs[t] = fmaxf(acc, 0.f);
  __syncthreads();
  if (t < nc) {
    float o = bc2[t];
    for (int k = 0; k < 128; k++) o += zs[k] * Wc2[k * nc + t];
    out[g * nc + t] = o;
  }
}

extern "C" void kernel_launch(void* const* d_in, const int* in_sizes, int n_in,
                              void* d_out, int out_size, void* d_ws, size_t ws_size,
                              hipStream_t stream) {
  const float* x   = (const float*)d_in[0];
  const int*   ei  = (const int*)d_in[1];
  const int*   bat = (const int*)d_in[2];
  const float* W1  = (const float*)d_in[3];
  const float* b1  = (const float*)d_in[4];
  const float* W2  = (const float*)d_in[5];
  const float* b2  = (const float*)d_in[6];
  const float* Wc1 = (const float*)d_in[7];
  const float* bc1 = (const float*)d_in[8];
  const float* Wc2 = (const float*)d_in[9];
  const float* bc2 = (const float*)d_in[10];
  float* out = (float*)d_out;

  const int N  = in_sizes[0] / 128;
  const int E  = in_sizes[1] / 2;
  const int NC = in_sizes[10];       // 10
  const int G  = out_size / NC;      // 64
  const int* src = ei;
  const int* dst = ei + E;
  (void)n_in; (void)ws_size;

  size_t off = 0;
  auto walloc = [&](size_t bytes) -> void* {
    void* p = (char*)d_ws + off;
    off += (bytes + 255) & ~(size_t)255;
    return p;
  };
  float* bufA   = (float*)walloc((size_t)N * 128 * 4);
  float* bufB   = (float*)walloc((size_t)N * 128 * 4);
  float* dinv   = (float*)walloc((size_t)N * 4);
  int*   cnt    = (int*)  walloc((size_t)N * 4);
  int*   rs     = (int*)  walloc((size_t)(N + 1) * 4);
  int*   cursor = (int*)  walloc((size_t)N * 4);
  int*   col    = (int*)  walloc((size_t)E * 4);
  float* nrm    = (float*)walloc((size_t)E * 4);
  float* pool   = (float*)walloc((size_t)G * 129 * 4);   // pool[G*128] then gcnt[G]
  float* gcnt   = pool + (size_t)G * 128;
  int*   partials = (int*)walloc(256 * 4);

  // CSR + norms
  hipMemsetAsync(cnt, 0, (size_t)N * 4, stream);
  count_edges_k<<<(E + 255) / 256, 256, 0, stream>>>(dst, E, cnt);
  int nb = (N + 1023) / 1024;
  scan1_k<<<nb, 1024, 0, stream>>>(cnt, rs, partials, N);
  scan2_k<<<1, 64, 0, stream>>>(partials, nb);
  scan3_k<<<(N + 255) / 256, 256, 0, stream>>>(rs, cursor, partials, N, E);
  dinv_k<<<(N + 255) / 256, 256, 0, stream>>>(cnt, dinv, N);
  fill_csr_k<<<(E + 255) / 256, 256, 0, stream>>>(src, dst, E, cursor, dinv, col, nrm);

  // layer 1: h = relu(Agg(x@W1) + b1)
  dim3 ggrid((N + 31) / 32, 2);
  gemm_k<<<ggrid, 256, 0, stream>>>(x, W1, bufA, N);
  agg_k<<<(N * 64 + 255) / 256, 256, 0, stream>>>(bufA, rs, col, nrm, dinv, b1, bufB, N);
  // layer 2
  gemm_k<<<ggrid, 256, 0, stream>>>(bufB, W2, bufA, N);
  agg_k<<<(N * 64 + 255) / 256, 256, 0, stream>>>(bufA, rs, col, nrm, dinv, b2, bufB, N);

  // mean pool + head
  hipMemsetAsync(pool, 0, (size_t)G * 129 * 4, stream);
  pool_k<<<(N + 63) / 64, 128, 0, stream>>>(bufB, bat, N, pool, gcnt);
  classify_k<<<G, 128, 0, stream>>>(pool, gcnt, Wc1, bc1, Wc2, bc2, out, NC);
}